// Round 1
// baseline (53620.416 us; speedup 1.0000x reference)
//
#include <hip/hip_runtime.h>
#include <cmath>

#define B_ 64
#define T_ 512
#define E_ 512
#define H_ 1024
#define O_ 512

typedef unsigned short ushort_t;
typedef __bf16 bf16x8 __attribute__((ext_vector_type(8)));
typedef float f32x4 __attribute__((ext_vector_type(4)));

__device__ __forceinline__ ushort_t f2bf(float f) {
    union { float f; unsigned int u; } x; x.f = f;
    unsigned int r = x.u + 0x7fffu + ((x.u >> 16) & 1u);
    return (ushort_t)(r >> 16);
}
__device__ __forceinline__ float bf2f(ushort_t u) {
    union { unsigned int u; float f; } x; x.u = ((unsigned int)u) << 16;
    return x.f;
}
__device__ __forceinline__ uint4 pack8bf(float4 v0, float4 v1) {
    uint4 pk;
    pk.x = (unsigned)f2bf(v0.x) | ((unsigned)f2bf(v0.y) << 16);
    pk.y = (unsigned)f2bf(v0.z) | ((unsigned)f2bf(v0.w) << 16);
    pk.z = (unsigned)f2bf(v1.x) | ((unsigned)f2bf(v1.y) << 16);
    pk.w = (unsigned)f2bf(v1.z) | ((unsigned)f2bf(v1.w) << 16);
    return pk;
}

// ---------------------------------------------------------------- prep ------
__global__ void prep_kernel(const float* __restrict__ h0, ushort_t* __restrict__ hinit,
                            int* __restrict__ bar) {
    int i = blockIdx.x * blockDim.x + threadIdx.x;
    if (i < 2) bar[i] = 0;
    if (i < 2 * B_ * H_) hinit[i] = f2bf(h0[i]);
}

// ------------------------------------------------ big GEMM: C = A*W^T + b ---
// MODE 0: A fp32 (emb, (B,T,E), row r=t*64+b -> emb row (b,t)), out bf16 direct rows
// MODE 1: A bf16 direct rows, out bf16 direct rows
// MODE 2: A bf16 direct rows, out fp32 remapped row r=t*64+b -> out row (b,t)
template <int MODE>
__launch_bounds__(256)
__global__ void gemm_bt(const void* __restrict__ Ap, const float* __restrict__ Wp,
                        const float* __restrict__ bias, void* __restrict__ outp,
                        int N, int K) {
    __shared__ __align__(16) ushort_t As[128 * 72];
    __shared__ __align__(16) ushort_t Bs[128 * 72];
    const int tid = threadIdx.x;
    const int lane = tid & 63;
    const int w = tid >> 6;
    const int wm = (w >> 1) * 64;
    const int wn = (w & 1) * 64;
    const int q = lane >> 4;
    const int l16 = lane & 15;
    const int m0 = blockIdx.y * 128;
    const int n0 = blockIdx.x * 128;

    const float*    Af = (const float*)Ap;
    const ushort_t* Ab = (const ushort_t*)Ap;

    f32x4 zero = {0.f, 0.f, 0.f, 0.f};
    f32x4 acc[4][4];
#pragma unroll
    for (int i = 0; i < 4; i++)
#pragma unroll
        for (int j = 0; j < 4; j++) acc[i][j] = zero;

    for (int k0 = 0; k0 < K; k0 += 64) {
#pragma unroll
        for (int it = 0; it < 4; it++) {
            int task = tid + it * 256;       // 1024 tasks: 128 rows x 8 segs
            int row = task >> 3, seg = task & 7;
            // ---- A tile
            if (MODE == 0) {
                int Ra = m0 + row;
                const float* src = Af + (size_t)((Ra & 63) * T_ + (Ra >> 6)) * K + k0 + seg * 8;
                float4 v0 = *(const float4*)src;
                float4 v1 = *(const float4*)(src + 4);
                *(uint4*)&As[row * 72 + seg * 8] = pack8bf(v0, v1);
            } else {
                const ushort_t* src = Ab + (size_t)(m0 + row) * K + k0 + seg * 8;
                *(uint4*)&As[row * 72 + seg * 8] = *(const uint4*)src;
            }
            // ---- B tile (weights always fp32, (N,K) row-major)
            const float* wsrc = Wp + (size_t)(n0 + row) * K + k0 + seg * 8;
            float4 w0 = *(const float4*)wsrc;
            float4 w1 = *(const float4*)(wsrc + 4);
            *(uint4*)&Bs[row * 72 + seg * 8] = pack8bf(w0, w1);
        }
        __syncthreads();
#pragma unroll
        for (int ks = 0; ks < 64; ks += 32) {
            bf16x8 af[4], bfr[4];
#pragma unroll
            for (int i = 0; i < 4; i++)
                af[i] = *(const bf16x8*)&As[(wm + i * 16 + l16) * 72 + ks + q * 8];
#pragma unroll
            for (int j = 0; j < 4; j++)
                bfr[j] = *(const bf16x8*)&Bs[(wn + j * 16 + l16) * 72 + ks + q * 8];
#pragma unroll
            for (int i = 0; i < 4; i++)
#pragma unroll
                for (int j = 0; j < 4; j++)
                    acc[i][j] = __builtin_amdgcn_mfma_f32_16x16x32_bf16(af[i], bfr[j], acc[i][j], 0, 0, 0);
        }
        __syncthreads();
    }

    // epilogue: D row = quad*4+reg (from A operand), col = lane&15 (from B operand)
#pragma unroll
    for (int j = 0; j < 4; j++) {
        int C = n0 + wn + j * 16 + l16;
        float bv = bias[C];
#pragma unroll
        for (int i = 0; i < 4; i++) {
#pragma unroll
            for (int r = 0; r < 4; r++) {
                int R = m0 + wm + i * 16 + q * 4 + r;
                float v = acc[i][j][r] + bv;
                if (MODE == 2) {
                    ((float*)outp)[(size_t)((R & 63) * T_ + (R >> 6)) * N + C] = v;
                } else {
                    ((ushort_t*)outp)[(size_t)R * N + C] = f2bf(v);
                }
            }
        }
    }
}

// -------------------------------------------- persistent recurrent layer ----
// grid = 256 blocks x 256 threads, 1 block/CU (co-resident).
// Block (bi,ni): batch rows [bi*16, bi*16+16), hidden cols [ni*16, ni*16+16).
// xall: (T,B,H) bf16, holds x[t] (input proj incl. b_ih); overwritten in place
// with h[t] -> becomes h_all for the next big GEMM.
__launch_bounds__(256, 1)
__global__ void rnn_layer(ushort_t* __restrict__ xall, const ushort_t* __restrict__ hinit,
                          const float* __restrict__ Whh, const float* __restrict__ bhh,
                          int* __restrict__ bar) {
    __shared__ __align__(16) ushort_t Ws[16 * 1032];  // W slice, padded stride
    __shared__ __align__(16) ushort_t Hs[16 * 1032];  // h_prev rows, padded
    __shared__ float Rs[4 * 16 * 17];                 // per-wave partial sums

    const int tid = threadIdx.x;
    const int lane = tid & 63;
    const int w = tid >> 6;
    const int q = lane >> 4;
    const int l16 = lane & 15;
    const int b0 = (blockIdx.x >> 6) << 4;  // 4 batch groups
    const int n0 = (blockIdx.x & 63) << 4;  // 64 col groups
    const int nblk = gridDim.x;

    // stage weight slice once: rows n0..n0+15 of Whh (H x H fp32) -> bf16 LDS
#pragma unroll
    for (int it = 0; it < 8; it++) {
        int task = tid + it * 256;   // 2048 tasks: 16 rows x 128 segs
        int row = task >> 7, seg = task & 127;
        const float* src = Whh + (size_t)(n0 + row) * H_ + seg * 8;
        float4 v0 = *(const float4*)src;
        float4 v1 = *(const float4*)(src + 4);
        *(uint4*)&Ws[row * 1032 + seg * 8] = pack8bf(v0, v1);
    }
    const float bv = bhh[n0 + (tid & 15)];

    for (int t = 0; t < T_; t++) {
        const ushort_t* hsrc = (t == 0) ? hinit : (xall + (size_t)(t - 1) * B_ * H_);
        // stage h_prev rows b0..b0+15, full H
#pragma unroll
        for (int it = 0; it < 8; it++) {
            int task = tid + it * 256;
            int row = task >> 7, seg = task & 127;
            *(uint4*)&Hs[row * 1032 + seg * 8] =
                *(const uint4*)(hsrc + (size_t)(b0 + row) * H_ + seg * 8);
        }
        __syncthreads();

        // wave w reduces K slice [w*256, w*256+256)
        f32x4 acc = {0.f, 0.f, 0.f, 0.f};
#pragma unroll
        for (int kk = 0; kk < 8; kk++) {
            int k = w * 256 + kk * 32 + q * 8;
            bf16x8 a = *(const bf16x8*)&Hs[l16 * 1032 + k];
            bf16x8 b = *(const bf16x8*)&Ws[l16 * 1032 + k];
            acc = __builtin_amdgcn_mfma_f32_16x16x32_bf16(a, b, acc, 0, 0, 0);
        }
#pragma unroll
        for (int r = 0; r < 4; r++) {
            int m = q * 4 + r;  // batch row within tile
            Rs[(w * 16 + m) * 17 + l16] = acc[r];
        }
        __syncthreads();

        // reduce 4 waves + epilogue: thread -> (m = tid>>4, n = tid&15)
        {
            int m = tid >> 4, n = tid & 15;
            float s = Rs[(0 * 16 + m) * 17 + n] + Rs[(1 * 16 + m) * 17 + n] +
                      Rs[(2 * 16 + m) * 17 + n] + Rs[(3 * 16 + m) * 17 + n];
            size_t xoff = (size_t)t * (B_ * H_) + (size_t)(b0 + m) * H_ + n0 + n;
            float x = bf2f(xall[xoff]);
            float h = tanhf(s + x + bv);
            xall[xoff] = f2bf(h);  // h[t] overwrites x[t] in place
        }

        if (t < T_ - 1) {
            __threadfence();   // agent release: drain + L2 writeback (cross-XCD)
            __syncthreads();
            if (tid == 0) {
                __hip_atomic_fetch_add(bar, 1, __ATOMIC_ACQ_REL, __HIP_MEMORY_SCOPE_AGENT);
                int target = nblk * (t + 1);
                while (__hip_atomic_load(bar, __ATOMIC_ACQUIRE, __HIP_MEMORY_SCOPE_AGENT) < target) {
                    __builtin_amdgcn_s_sleep(2);
                }
            }
            __syncthreads();
            __threadfence();   // agent acquire: invalidate L1/L2 stale lines
        }
    }
}

// ---------------------------------------------------------------- launch ----
extern "C" void kernel_launch(void* const* d_in, const int* in_sizes, int n_in,
                              void* d_out, int out_size, void* d_ws, size_t ws_size,
                              hipStream_t stream) {
    (void)in_sizes; (void)n_in; (void)out_size; (void)ws_size;
    const float* emb   = (const float*)d_in[0];
    const float* h0    = (const float*)d_in[1];
    const float* W_ih0 = (const float*)d_in[2];
    const float* b_ih0 = (const float*)d_in[3];
    const float* W_ih1 = (const float*)d_in[4];
    const float* b_ih1 = (const float*)d_in[5];
    const float* W_hh0 = (const float*)d_in[6];
    const float* b_hh0 = (const float*)d_in[7];
    const float* W_hh1 = (const float*)d_in[8];
    const float* b_hh1 = (const float*)d_in[9];
    const float* W_out = (const float*)d_in[10];
    const float* b_out = (const float*)d_in[11];
    float* out = (float*)d_out;

    char* ws = (char*)d_ws;
    int*      bar   = (int*)ws;                              // 2 barrier counters
    ushort_t* hinit = (ushort_t*)(ws + 1024);                // 2*B*H bf16
    ushort_t* xp    = (ushort_t*)(ws + 1024 + 2 * B_ * H_ * 2);  // (T,B,H) bf16
    ushort_t* xq    = xp + (size_t)T_ * B_ * H_;                 // (T,B,H) bf16

    prep_kernel<<<512, 256, 0, stream>>>(h0, hinit, bar);

    // xp = emb . W_ih0^T + b_ih0   (stored (T,B,H))
    gemm_bt<0><<<dim3(H_ / 128, (B_ * T_) / 128), 256, 0, stream>>>(
        emb, W_ih0, b_ih0, xp, H_, E_);

    // layer-0 recurrence (xp -> h0_all, in place)
    rnn_layer<<<256, 256, 0, stream>>>(xp, hinit, W_hh0, b_hh0, bar + 0);

    // xq = h0_all . W_ih1^T + b_ih1
    gemm_bt<1><<<dim3(H_ / 128, (B_ * T_) / 128), 256, 0, stream>>>(
        xp, W_ih1, b_ih1, xq, H_, H_);

    // layer-1 recurrence (xq -> h1_all, in place)
    rnn_layer<<<256, 256, 0, stream>>>(xq, hinit + B_ * H_, W_hh1, b_hh1, bar + 1);

    // out = h1_all . W_out^T + b_out   ((B,T,O) fp32)
    gemm_bt<2><<<dim3(O_ / 128, (B_ * T_) / 128), 256, 0, stream>>>(
        xq, W_out, b_out, out, O_, H_);
}

// Round 2
// 3361.897 us; speedup vs baseline: 15.9495x; 15.9495x over previous
//
#include <hip/hip_runtime.h>
#include <cmath>

#define B_ 64
#define T_ 512
#define E_ 512
#define H_ 1024
#define O_ 512

typedef unsigned short ushort_t;
typedef __bf16 bf16x8 __attribute__((ext_vector_type(8)));
typedef float f32x4 __attribute__((ext_vector_type(4)));

__device__ __forceinline__ ushort_t f2bf(float f) {
    union { float f; unsigned int u; } x; x.f = f;
    unsigned int r = x.u + 0x7fffu + ((x.u >> 16) & 1u);
    return (ushort_t)(r >> 16);
}
__device__ __forceinline__ float bf2f(ushort_t u) {
    union { unsigned int u; float f; } x; x.u = ((unsigned int)u) << 16;
    return x.f;
}
__device__ __forceinline__ uint4 pack8bf(float4 v0, float4 v1) {
    uint4 pk;
    pk.x = (unsigned)f2bf(v0.x) | ((unsigned)f2bf(v0.y) << 16);
    pk.y = (unsigned)f2bf(v0.z) | ((unsigned)f2bf(v0.w) << 16);
    pk.z = (unsigned)f2bf(v1.x) | ((unsigned)f2bf(v1.y) << 16);
    pk.w = (unsigned)f2bf(v1.z) | ((unsigned)f2bf(v1.w) << 16);
    return pk;
}

// ---------------------------------------------------------------- prep ------
__global__ void prep_kernel(const float* __restrict__ h0, ushort_t* __restrict__ hinit,
                            int* __restrict__ bar) {
    int i = blockIdx.x * blockDim.x + threadIdx.x;
    if (i < 512) bar[i] = 0;   // both layers' barrier regions (4 groups x 64-int spacing x 2)
    if (i < 2 * B_ * H_) hinit[i] = f2bf(h0[i]);
}

// ------------------------------------------------ big GEMM: C = A*W^T + b ---
// MODE 0: A fp32 (emb, (B,T,E), row r=t*64+b -> emb row (b,t)), out bf16 direct rows
// MODE 1: A bf16 direct rows, out bf16 direct rows
// MODE 2: A bf16 direct rows, out fp32 remapped row r=t*64+b -> out row (b,t)
template <int MODE>
__launch_bounds__(256)
__global__ void gemm_bt(const void* __restrict__ Ap, const float* __restrict__ Wp,
                        const float* __restrict__ bias, void* __restrict__ outp,
                        int N, int K) {
    __shared__ __align__(16) ushort_t As[128 * 72];
    __shared__ __align__(16) ushort_t Bs[128 * 72];
    const int tid = threadIdx.x;
    const int lane = tid & 63;
    const int w = tid >> 6;
    const int wm = (w >> 1) * 64;
    const int wn = (w & 1) * 64;
    const int q = lane >> 4;
    const int l16 = lane & 15;
    const int m0 = blockIdx.y * 128;
    const int n0 = blockIdx.x * 128;

    const float*    Af = (const float*)Ap;
    const ushort_t* Ab = (const ushort_t*)Ap;

    f32x4 zero = {0.f, 0.f, 0.f, 0.f};
    f32x4 acc[4][4];
#pragma unroll
    for (int i = 0; i < 4; i++)
#pragma unroll
        for (int j = 0; j < 4; j++) acc[i][j] = zero;

    for (int k0 = 0; k0 < K; k0 += 64) {
#pragma unroll
        for (int it = 0; it < 4; it++) {
            int task = tid + it * 256;       // 1024 tasks: 128 rows x 8 segs
            int row = task >> 3, seg = task & 7;
            // ---- A tile
            if (MODE == 0) {
                int Ra = m0 + row;
                const float* src = Af + (size_t)((Ra & 63) * T_ + (Ra >> 6)) * K + k0 + seg * 8;
                float4 v0 = *(const float4*)src;
                float4 v1 = *(const float4*)(src + 4);
                *(uint4*)&As[row * 72 + seg * 8] = pack8bf(v0, v1);
            } else {
                const ushort_t* src = Ab + (size_t)(m0 + row) * K + k0 + seg * 8;
                *(uint4*)&As[row * 72 + seg * 8] = *(const uint4*)src;
            }
            // ---- B tile (weights always fp32, (N,K) row-major)
            const float* wsrc = Wp + (size_t)(n0 + row) * K + k0 + seg * 8;
            float4 w0 = *(const float4*)wsrc;
            float4 w1 = *(const float4*)(wsrc + 4);
            *(uint4*)&Bs[row * 72 + seg * 8] = pack8bf(w0, w1);
        }
        __syncthreads();
#pragma unroll
        for (int ks = 0; ks < 64; ks += 32) {
            bf16x8 af[4], bfr[4];
#pragma unroll
            for (int i = 0; i < 4; i++)
                af[i] = *(const bf16x8*)&As[(wm + i * 16 + l16) * 72 + ks + q * 8];
#pragma unroll
            for (int j = 0; j < 4; j++)
                bfr[j] = *(const bf16x8*)&Bs[(wn + j * 16 + l16) * 72 + ks + q * 8];
#pragma unroll
            for (int i = 0; i < 4; i++)
#pragma unroll
                for (int j = 0; j < 4; j++)
                    acc[i][j] = __builtin_amdgcn_mfma_f32_16x16x32_bf16(af[i], bfr[j], acc[i][j], 0, 0, 0);
        }
        __syncthreads();
    }

#pragma unroll
    for (int j = 0; j < 4; j++) {
        int C = n0 + wn + j * 16 + l16;
        float bv = bias[C];
#pragma unroll
        for (int i = 0; i < 4; i++) {
#pragma unroll
            for (int r = 0; r < 4; r++) {
                int R = m0 + wm + i * 16 + q * 4 + r;
                float v = acc[i][j][r] + bv;
                if (MODE == 2) {
                    ((float*)outp)[(size_t)((R & 63) * T_ + (R >> 6)) * N + C] = v;
                } else {
                    ((ushort_t*)outp)[(size_t)R * N + C] = f2bf(v);
                }
            }
        }
    }
}

// -------------------------------------------- persistent recurrent layer ----
// grid = 256 blocks x 256 threads, 1 block/CU (co-resident).
// Block (bi,ni): batch rows [bi*16,+16), hidden cols [ni*16,+16).
// Cross-block h traffic uses sc0 sc1 (LLC-coherent) accesses ONLY — no
// wbl2/inv cache maintenance. Barrier: per-batch-group (64 blocks), relaxed
// system-scope atomics; __syncthreads' vmcnt(0) drain provides ordering.
__launch_bounds__(256, 1)
__global__ void rnn_layer(ushort_t* __restrict__ xall, const ushort_t* __restrict__ hinit,
                          const float* __restrict__ Whh, const float* __restrict__ bhh,
                          int* __restrict__ bar) {
    __shared__ __align__(16) ushort_t Ws[16 * 1032];  // W slice, padded stride
    __shared__ __align__(16) ushort_t Hs[16 * 1032];  // h_prev rows, padded
    __shared__ float Rs[4 * 16 * 17];                 // per-wave partial sums

    const int tid = threadIdx.x;
    const int lane = tid & 63;
    const int w = tid >> 6;
    const int q = lane >> 4;
    const int l16 = lane & 15;
    const int b0 = (blockIdx.x >> 6) << 4;  // 4 batch groups
    const int n0 = (blockIdx.x & 63) << 4;  // 64 col groups
    int* barg = bar + (blockIdx.x >> 6) * 64;  // group counter, 256B apart

    // stage weight slice once: rows n0..n0+15 of Whh (H x H fp32) -> bf16 LDS
#pragma unroll
    for (int it = 0; it < 8; it++) {
        int task = tid + it * 256;   // 2048 tasks: 16 rows x 128 segs
        int row = task >> 7, seg = task & 127;
        const float* src = Whh + (size_t)(n0 + row) * H_ + seg * 8;
        float4 v0 = *(const float4*)src;
        float4 v1 = *(const float4*)(src + 4);
        *(uint4*)&Ws[row * 1032 + seg * 8] = pack8bf(v0, v1);
    }

    // epilogue thread mapping (threads 0..127): row m, col pair n2
    const int em = tid >> 3;
    const int en2 = (tid & 7) * 2;
    float bv0 = 0.f, bv1 = 0.f;
    if (tid < 128) { bv0 = bhh[n0 + en2]; bv1 = bhh[n0 + en2 + 1]; }

    // staging address components: 8 x dwordx4 per thread, perfectly coalesced
    const int rbase = tid >> 7;      // 0/1
    const int seg = tid & 127;       // 16B segment within row

    for (int t = 0; t < T_; t++) {
        const ushort_t* hsrc = (t == 0) ? hinit : (xall + (size_t)(t - 1) * B_ * H_);
        const ushort_t* p0 = hsrc + (size_t)(b0 + rbase) * H_ + seg * 8;
        const ushort_t* p1 = p0 + 2 * H_;
        const ushort_t* p2 = p0 + 4 * H_;
        const ushort_t* p3 = p0 + 6 * H_;
        const ushort_t* p4 = p0 + 8 * H_;
        const ushort_t* p5 = p0 + 10 * H_;
        const ushort_t* p6 = p0 + 12 * H_;
        const ushort_t* p7 = p0 + 14 * H_;
        uint4 v0, v1, v2, v3, v4, v5, v6, v7;
        asm volatile(
            "global_load_dwordx4 %0, %8, off sc0 sc1\n\t"
            "global_load_dwordx4 %1, %9, off sc0 sc1\n\t"
            "global_load_dwordx4 %2, %10, off sc0 sc1\n\t"
            "global_load_dwordx4 %3, %11, off sc0 sc1\n\t"
            "global_load_dwordx4 %4, %12, off sc0 sc1\n\t"
            "global_load_dwordx4 %5, %13, off sc0 sc1\n\t"
            "global_load_dwordx4 %6, %14, off sc0 sc1\n\t"
            "global_load_dwordx4 %7, %15, off sc0 sc1\n\t"
            "s_waitcnt vmcnt(0)"
            : "=&v"(v0), "=&v"(v1), "=&v"(v2), "=&v"(v3),
              "=&v"(v4), "=&v"(v5), "=&v"(v6), "=&v"(v7)
            : "v"(p0), "v"(p1), "v"(p2), "v"(p3),
              "v"(p4), "v"(p5), "v"(p6), "v"(p7)
            : "memory");
        *(uint4*)&Hs[(rbase + 0) * 1032 + seg * 8] = v0;
        *(uint4*)&Hs[(rbase + 2) * 1032 + seg * 8] = v1;
        *(uint4*)&Hs[(rbase + 4) * 1032 + seg * 8] = v2;
        *(uint4*)&Hs[(rbase + 6) * 1032 + seg * 8] = v3;
        *(uint4*)&Hs[(rbase + 8) * 1032 + seg * 8] = v4;
        *(uint4*)&Hs[(rbase + 10) * 1032 + seg * 8] = v5;
        *(uint4*)&Hs[(rbase + 12) * 1032 + seg * 8] = v6;
        *(uint4*)&Hs[(rbase + 14) * 1032 + seg * 8] = v7;
        __syncthreads();

        // wave w reduces K slice [w*256, w*256+256)
        f32x4 acc = {0.f, 0.f, 0.f, 0.f};
#pragma unroll
        for (int kk = 0; kk < 8; kk++) {
            int k = w * 256 + kk * 32 + q * 8;
            bf16x8 a = *(const bf16x8*)&Hs[l16 * 1032 + k];
            bf16x8 b = *(const bf16x8*)&Ws[l16 * 1032 + k];
            acc = __builtin_amdgcn_mfma_f32_16x16x32_bf16(a, b, acc, 0, 0, 0);
        }
#pragma unroll
        for (int r = 0; r < 4; r++) {
            int m = q * 4 + r;
            Rs[(w * 16 + m) * 17 + l16] = acc[r];
        }
        __syncthreads();

        // reduce 4 waves + tanh epilogue; coherent 4B store of a col-pair
        if (tid < 128) {
            float s0 = Rs[(0 * 16 + em) * 17 + en2] + Rs[(1 * 16 + em) * 17 + en2] +
                       Rs[(2 * 16 + em) * 17 + en2] + Rs[(3 * 16 + em) * 17 + en2];
            float s1 = Rs[(0 * 16 + em) * 17 + en2 + 1] + Rs[(1 * 16 + em) * 17 + en2 + 1] +
                       Rs[(2 * 16 + em) * 17 + en2 + 1] + Rs[(3 * 16 + em) * 17 + en2 + 1];
            size_t xoff = (size_t)t * (B_ * H_) + (size_t)(b0 + em) * H_ + n0 + en2;
            unsigned int xv = *(const unsigned int*)(xall + xoff);  // x never written before
            float h0v = tanhf(s0 + bf2f((ushort_t)(xv & 0xffff)) + bv0);
            float h1v = tanhf(s1 + bf2f((ushort_t)(xv >> 16)) + bv1);
            unsigned int pk = (unsigned)f2bf(h0v) | ((unsigned)f2bf(h1v) << 16);
            __hip_atomic_store((unsigned int*)(xall + xoff), pk,
                               __ATOMIC_RELAXED, __HIP_MEMORY_SCOPE_SYSTEM);
        }

        if (t < T_ - 1) {
            __syncthreads();  // per-wave vmcnt(0) drain: all h stores LLC-visible
            if (tid == 0) {
                __hip_atomic_fetch_add(barg, 1, __ATOMIC_RELAXED, __HIP_MEMORY_SCOPE_SYSTEM);
                int target = 64 * (t + 1);
                while (__hip_atomic_load(barg, __ATOMIC_RELAXED, __HIP_MEMORY_SCOPE_SYSTEM) < target) {
                    __builtin_amdgcn_s_sleep(1);
                }
            }
            __syncthreads();
        }
    }
}

// ---------------------------------------------------------------- launch ----
extern "C" void kernel_launch(void* const* d_in, const int* in_sizes, int n_in,
                              void* d_out, int out_size, void* d_ws, size_t ws_size,
                              hipStream_t stream) {
    (void)in_sizes; (void)n_in; (void)out_size; (void)ws_size;
    const float* emb   = (const float*)d_in[0];
    const float* h0    = (const float*)d_in[1];
    const float* W_ih0 = (const float*)d_in[2];
    const float* b_ih0 = (const float*)d_in[3];
    const float* W_ih1 = (const float*)d_in[4];
    const float* b_ih1 = (const float*)d_in[5];
    const float* W_hh0 = (const float*)d_in[6];
    const float* b_hh0 = (const float*)d_in[7];
    const float* W_hh1 = (const float*)d_in[8];
    const float* b_hh1 = (const float*)d_in[9];
    const float* W_out = (const float*)d_in[10];
    const float* b_out = (const float*)d_in[11];
    float* out = (float*)d_out;

    char* ws = (char*)d_ws;
    int*      bar   = (int*)ws;                      // layer0: +0, layer1: +1024B
    ushort_t* hinit = (ushort_t*)(ws + 4096);        // 2*B*H bf16
    ushort_t* xp    = (ushort_t*)(ws + 4096 + 2 * B_ * H_ * 2);  // (T,B,H) bf16
    ushort_t* xq    = xp + (size_t)T_ * B_ * H_;                 // (T,B,H) bf16

    prep_kernel<<<512, 256, 0, stream>>>(h0, hinit, bar);

    gemm_bt<0><<<dim3(H_ / 128, (B_ * T_) / 128), 256, 0, stream>>>(
        emb, W_ih0, b_ih0, xp, H_, E_);

    rnn_layer<<<256, 256, 0, stream>>>(xp, hinit, W_hh0, b_hh0, bar);

    gemm_bt<1><<<dim3(H_ / 128, (B_ * T_) / 128), 256, 0, stream>>>(
        xp, W_ih1, b_ih1, xq, H_, H_);

    rnn_layer<<<256, 256, 0, stream>>>(xq, hinit + B_ * H_, W_hh1, b_hh1, bar + 256);

    gemm_bt<2><<<dim3(O_ / 128, (B_ * T_) / 128), 256, 0, stream>>>(
        xq, W_out, b_out, out, O_, H_);
}

// Round 5
// 3119.729 us; speedup vs baseline: 17.1875x; 1.0776x over previous
//
#include <hip/hip_runtime.h>
#include <cmath>

#define B_ 64
#define T_ 512
#define E_ 512
#define H_ 1024
#define O_ 512
#define BH (B_ * H_)
#define HSTRIDE 1160  // LDS row stride (elems)

typedef unsigned short ushort_t;
typedef __bf16 bf16x8 __attribute__((ext_vector_type(8)));
typedef float f32x4 __attribute__((ext_vector_type(4)));

__device__ __forceinline__ ushort_t f2bf(float f) {
    union { float f; unsigned int u; } x; x.f = f;
    unsigned int r = x.u + 0x7fffu + ((x.u >> 16) & 1u);
    return (ushort_t)(r >> 16);
}
__device__ __forceinline__ float bf2f(ushort_t u) {
    union { unsigned int u; float f; } x; x.u = ((unsigned int)u) << 16;
    return x.f;
}
__device__ __forceinline__ uint4 pack8bf(float4 v0, float4 v1) {
    uint4 pk;
    pk.x = (unsigned)f2bf(v0.x) | ((unsigned)f2bf(v0.y) << 16);
    pk.y = (unsigned)f2bf(v0.z) | ((unsigned)f2bf(v0.w) << 16);
    pk.z = (unsigned)f2bf(v1.x) | ((unsigned)f2bf(v1.y) << 16);
    pk.w = (unsigned)f2bf(v1.z) | ((unsigned)f2bf(v1.w) << 16);
    return pk;
}
__device__ __forceinline__ bf16x8 pack8(const float* src) {
    float4 v0 = *(const float4*)src;
    float4 v1 = *(const float4*)(src + 4);
    union { uint4 u; bf16x8 b; } c;
    c.u = pack8bf(v0, v1);
    return c.b;
}

// ---------------------------------------------------------------- prep ------
__global__ void prep_kernel(const float* __restrict__ h0, ushort_t* __restrict__ hinit,
                            int* __restrict__ bar) {
    int i = blockIdx.x * blockDim.x + threadIdx.x;
    if (i < 1024) bar[i] = 0;
    if (i < 2 * BH) hinit[i] = f2bf(h0[i]);
}

// ------------------------------------------------ big GEMM: C = A*W^T + b ---
// MODE 0: A fp32 (emb, (B,T,E), row r=t*64+b -> emb row (b,t)), out bf16 direct rows
// MODE 2: A bf16 direct rows, out fp32 remapped row r=t*64+b -> out row (b,t)
template <int MODE>
__launch_bounds__(256)
__global__ void gemm_bt(const void* __restrict__ Ap, const float* __restrict__ Wp,
                        const float* __restrict__ bias, void* __restrict__ outp,
                        int N, int K) {
    __shared__ __align__(16) ushort_t As[128 * 72];
    __shared__ __align__(16) ushort_t Bs[128 * 72];
    const int tid = threadIdx.x;
    const int lane = tid & 63;
    const int w = tid >> 6;
    const int wm = (w >> 1) * 64;
    const int wn = (w & 1) * 64;
    const int q = lane >> 4;
    const int l16 = lane & 15;
    const int m0 = blockIdx.y * 128;
    const int n0 = blockIdx.x * 128;

    const float*    Af = (const float*)Ap;
    const ushort_t* Ab = (const ushort_t*)Ap;

    f32x4 zero = {0.f, 0.f, 0.f, 0.f};
    f32x4 acc[4][4];
#pragma unroll
    for (int i = 0; i < 4; i++)
#pragma unroll
        for (int j = 0; j < 4; j++) acc[i][j] = zero;

    for (int k0 = 0; k0 < K; k0 += 64) {
#pragma unroll
        for (int it = 0; it < 4; it++) {
            int task = tid + it * 256;
            int row = task >> 3, seg = task & 7;
            if (MODE == 0) {
                int Ra = m0 + row;
                const float* src = Af + (size_t)((Ra & 63) * T_ + (Ra >> 6)) * K + k0 + seg * 8;
                float4 v0 = *(const float4*)src;
                float4 v1 = *(const float4*)(src + 4);
                *(uint4*)&As[row * 72 + seg * 8] = pack8bf(v0, v1);
            } else {
                const ushort_t* src = Ab + (size_t)(m0 + row) * K + k0 + seg * 8;
                *(uint4*)&As[row * 72 + seg * 8] = *(const uint4*)src;
            }
            const float* wsrc = Wp + (size_t)(n0 + row) * K + k0 + seg * 8;
            float4 w0 = *(const float4*)wsrc;
            float4 w1 = *(const float4*)(wsrc + 4);
            *(uint4*)&Bs[row * 72 + seg * 8] = pack8bf(w0, w1);
        }
        __syncthreads();
#pragma unroll
        for (int ks = 0; ks < 64; ks += 32) {
            bf16x8 af[4], bfr[4];
#pragma unroll
            for (int i = 0; i < 4; i++)
                af[i] = *(const bf16x8*)&As[(wm + i * 16 + l16) * 72 + ks + q * 8];
#pragma unroll
            for (int j = 0; j < 4; j++)
                bfr[j] = *(const bf16x8*)&Bs[(wn + j * 16 + l16) * 72 + ks + q * 8];
#pragma unroll
            for (int i = 0; i < 4; i++)
#pragma unroll
                for (int j = 0; j < 4; j++)
                    acc[i][j] = __builtin_amdgcn_mfma_f32_16x16x32_bf16(af[i], bfr[j], acc[i][j], 0, 0, 0);
        }
        __syncthreads();
    }

#pragma unroll
    for (int j = 0; j < 4; j++) {
        int C = n0 + wn + j * 16 + l16;
        float bv = bias[C];
#pragma unroll
        for (int i = 0; i < 4; i++) {
#pragma unroll
            for (int r = 0; r < 4; r++) {
                int R = m0 + wm + i * 16 + q * 4 + r;
                float v = acc[i][j][r] + bv;
                if (MODE == 2) {
                    ((float*)outp)[(size_t)((R & 63) * T_ + (R >> 6)) * N + C] = v;
                } else {
                    ((ushort_t*)outp)[(size_t)R * N + C] = f2bf(v);
                }
            }
        }
    }
}

// -------------------------- single-layer persistent recurrence (no skew) ----
// 128 blocks x 256 threads. Block (gb, nc): batch rows [16gb,+16), cols [32nc,+32).
// LAYER 0: h[r] = tanh(h[r-1]·Wa^T + x_r + ba), x_r read in-place from xall[r],
//          h[r] overwrites xall[r]. Recurrent dep only -> group barrier.
// LAYER 1: h[r] = tanh(xsrc[r]·Wa^T + h[r-1]·Wb^T + ba+bb). xsrc (=h0_all) is
//          FULLY materialized by the previous dispatch -> no sync on that path;
//          group barrier covers only the xall (h1) recurrence.
// This isolates the R3/R4 fused machinery (register B-fragments, 32-col blocks,
// sc0sc1 asm staging, dual-matrix accumulate) from the cross-layer skew.
template <int LAYER>
__launch_bounds__(256, 1)
__global__ void rnn_pass(ushort_t* __restrict__ xall,
                         const ushort_t* __restrict__ xsrc,
                         const ushort_t* __restrict__ hin,
                         const float* __restrict__ Wa, const float* __restrict__ Wb,
                         const float* __restrict__ ba, const float* __restrict__ bb,
                         int* __restrict__ bar) {
    __shared__ __align__(16) ushort_t Hs0[16 * HSTRIDE];  // x-source rows (LAYER 1)
    __shared__ __align__(16) ushort_t Hs1[16 * HSTRIDE];  // recurrent-state rows
    __shared__ float Rs[4][16][33];

    const int tid = threadIdx.x;
    const int lane = tid & 63;
    const int w = tid >> 6;
    const int q = lane >> 4;
    const int l16 = lane & 15;
    const int gb = blockIdx.x >> 5;       // 4 batch groups x 32 col blocks
    const int b0 = gb * 16;
    const int n0 = (blockIdx.x & 31) * 32;
    int* cnt = bar + LAYER * 256 + gb * 64;

    // ---- register B-fragments (loop-invariant weights)
    bf16x8 wA[16], wB[16];
#pragma unroll
    for (int g = 0; g < 2; g++)
#pragma unroll
        for (int kk = 0; kk < 8; kk++) {
            size_t off = (size_t)(n0 + g * 16 + l16) * H_ + w * 256 + kk * 32 + q * 8;
            wA[g * 8 + kk] = pack8(Wa + off);
            if (LAYER == 1) wB[g * 8 + kk] = pack8(Wb + off);
        }

    const int em = tid >> 4;
    const int en = (tid & 15) * 2;
    float bv0 = ba[n0 + en], bv1 = ba[n0 + en + 1];
    if (LAYER == 1) { bv0 += bb[n0 + en]; bv1 += bb[n0 + en + 1]; }

    const int rbase2 = (tid >> 7) * 2;  // 0 or 2
    const int seg = tid & 127;

    for (int r = 0; r < 512; r++) {
        // ---- stage recurrent state rows (and x-source rows for LAYER 1)
        const ushort_t* s1 = (r == 0) ? hin : (xall + (size_t)(r - 1) * BH);
        const ushort_t* c0 = s1 + (size_t)(b0 + rbase2) * H_ + seg * 8;
        const ushort_t* c1 = c0 + 4 * H_;
        const ushort_t* c2 = c0 + 8 * H_;
        const ushort_t* c3 = c0 + 12 * H_;
        if (LAYER == 0) {
            uint4 d0, d1, d2, d3, d4, d5, d6, d7;
            asm volatile(
                "global_load_dwordx4 %0, %8, off sc0 sc1\n\t"
                "global_load_dwordx4 %1, %8, off offset:2048 sc0 sc1\n\t"
                "global_load_dwordx4 %2, %9, off sc0 sc1\n\t"
                "global_load_dwordx4 %3, %9, off offset:2048 sc0 sc1\n\t"
                "global_load_dwordx4 %4, %10, off sc0 sc1\n\t"
                "global_load_dwordx4 %5, %10, off offset:2048 sc0 sc1\n\t"
                "global_load_dwordx4 %6, %11, off sc0 sc1\n\t"
                "global_load_dwordx4 %7, %11, off offset:2048 sc0 sc1\n\t"
                "s_waitcnt vmcnt(0)"
                : "=&v"(d0), "=&v"(d1), "=&v"(d2), "=&v"(d3),
                  "=&v"(d4), "=&v"(d5), "=&v"(d6), "=&v"(d7)
                : "v"(c0), "v"(c1), "v"(c2), "v"(c3)
                : "memory");
            *(uint4*)&Hs1[(rbase2 + 0) * HSTRIDE + seg * 8] = d0;
            *(uint4*)&Hs1[(rbase2 + 1) * HSTRIDE + seg * 8] = d1;
            *(uint4*)&Hs1[(rbase2 + 4) * HSTRIDE + seg * 8] = d2;
            *(uint4*)&Hs1[(rbase2 + 5) * HSTRIDE + seg * 8] = d3;
            *(uint4*)&Hs1[(rbase2 + 8) * HSTRIDE + seg * 8] = d4;
            *(uint4*)&Hs1[(rbase2 + 9) * HSTRIDE + seg * 8] = d5;
            *(uint4*)&Hs1[(rbase2 + 12) * HSTRIDE + seg * 8] = d6;
            *(uint4*)&Hs1[(rbase2 + 13) * HSTRIDE + seg * 8] = d7;
        } else {
            const ushort_t* a0 = xsrc + (size_t)r * BH + (size_t)(b0 + rbase2) * H_ + seg * 8;
            const ushort_t* a1 = a0 + 4 * H_;
            const ushort_t* a2 = a0 + 8 * H_;
            const ushort_t* a3 = a0 + 12 * H_;
            uint4 d0, d1, d2, d3, d4, d5, d6, d7;
            uint4 e0, e1, e2, e3, e4, e5, e6, e7;
            asm volatile(
                "global_load_dwordx4 %0, %16, off sc0 sc1\n\t"
                "global_load_dwordx4 %1, %16, off offset:2048 sc0 sc1\n\t"
                "global_load_dwordx4 %2, %17, off sc0 sc1\n\t"
                "global_load_dwordx4 %3, %17, off offset:2048 sc0 sc1\n\t"
                "global_load_dwordx4 %4, %18, off sc0 sc1\n\t"
                "global_load_dwordx4 %5, %18, off offset:2048 sc0 sc1\n\t"
                "global_load_dwordx4 %6, %19, off sc0 sc1\n\t"
                "global_load_dwordx4 %7, %19, off offset:2048 sc0 sc1\n\t"
                "global_load_dwordx4 %8, %20, off sc0 sc1\n\t"
                "global_load_dwordx4 %9, %20, off offset:2048 sc0 sc1\n\t"
                "global_load_dwordx4 %10, %21, off sc0 sc1\n\t"
                "global_load_dwordx4 %11, %21, off offset:2048 sc0 sc1\n\t"
                "global_load_dwordx4 %12, %22, off sc0 sc1\n\t"
                "global_load_dwordx4 %13, %22, off offset:2048 sc0 sc1\n\t"
                "global_load_dwordx4 %14, %23, off sc0 sc1\n\t"
                "global_load_dwordx4 %15, %23, off offset:2048 sc0 sc1\n\t"
                "s_waitcnt vmcnt(0)"
                : "=&v"(d0), "=&v"(d1), "=&v"(d2), "=&v"(d3),
                  "=&v"(d4), "=&v"(d5), "=&v"(d6), "=&v"(d7),
                  "=&v"(e0), "=&v"(e1), "=&v"(e2), "=&v"(e3),
                  "=&v"(e4), "=&v"(e5), "=&v"(e6), "=&v"(e7)
                : "v"(a0), "v"(a1), "v"(a2), "v"(a3),
                  "v"(c0), "v"(c1), "v"(c2), "v"(c3)
                : "memory");
            *(uint4*)&Hs0[(rbase2 + 0) * HSTRIDE + seg * 8] = d0;
            *(uint4*)&Hs0[(rbase2 + 1) * HSTRIDE + seg * 8] = d1;
            *(uint4*)&Hs0[(rbase2 + 4) * HSTRIDE + seg * 8] = d2;
            *(uint4*)&Hs0[(rbase2 + 5) * HSTRIDE + seg * 8] = d3;
            *(uint4*)&Hs0[(rbase2 + 8) * HSTRIDE + seg * 8] = d4;
            *(uint4*)&Hs0[(rbase2 + 9) * HSTRIDE + seg * 8] = d5;
            *(uint4*)&Hs0[(rbase2 + 12) * HSTRIDE + seg * 8] = d6;
            *(uint4*)&Hs0[(rbase2 + 13) * HSTRIDE + seg * 8] = d7;
            *(uint4*)&Hs1[(rbase2 + 0) * HSTRIDE + seg * 8] = e0;
            *(uint4*)&Hs1[(rbase2 + 1) * HSTRIDE + seg * 8] = e1;
            *(uint4*)&Hs1[(rbase2 + 4) * HSTRIDE + seg * 8] = e2;
            *(uint4*)&Hs1[(rbase2 + 5) * HSTRIDE + seg * 8] = e3;
            *(uint4*)&Hs1[(rbase2 + 8) * HSTRIDE + seg * 8] = e4;
            *(uint4*)&Hs1[(rbase2 + 9) * HSTRIDE + seg * 8] = e5;
            *(uint4*)&Hs1[(rbase2 + 12) * HSTRIDE + seg * 8] = e6;
            *(uint4*)&Hs1[(rbase2 + 13) * HSTRIDE + seg * 8] = e7;
        }
        __syncthreads();

        // ---- MFMA: wave w covers K slice [256w,+256), both 16-col groups
        f32x4 acc0 = {0.f, 0.f, 0.f, 0.f};
        f32x4 acc1 = {0.f, 0.f, 0.f, 0.f};
        const int kb = w * 256;
        if (LAYER == 1) {
#pragma unroll
            for (int kk = 0; kk < 8; kk++) {
                bf16x8 a = *(const bf16x8*)&Hs0[l16 * HSTRIDE + kb + kk * 32 + q * 8];
                acc0 = __builtin_amdgcn_mfma_f32_16x16x32_bf16(a, wA[kk], acc0, 0, 0, 0);
                acc1 = __builtin_amdgcn_mfma_f32_16x16x32_bf16(a, wA[8 + kk], acc1, 0, 0, 0);
            }
#pragma unroll
            for (int kk = 0; kk < 8; kk++) {
                bf16x8 a = *(const bf16x8*)&Hs1[l16 * HSTRIDE + kb + kk * 32 + q * 8];
                acc0 = __builtin_amdgcn_mfma_f32_16x16x32_bf16(a, wB[kk], acc0, 0, 0, 0);
                acc1 = __builtin_amdgcn_mfma_f32_16x16x32_bf16(a, wB[8 + kk], acc1, 0, 0, 0);
            }
        } else {
#pragma unroll
            for (int kk = 0; kk < 8; kk++) {
                bf16x8 a = *(const bf16x8*)&Hs1[l16 * HSTRIDE + kb + kk * 32 + q * 8];
                acc0 = __builtin_amdgcn_mfma_f32_16x16x32_bf16(a, wA[kk], acc0, 0, 0, 0);
                acc1 = __builtin_amdgcn_mfma_f32_16x16x32_bf16(a, wA[8 + kk], acc1, 0, 0, 0);
            }
        }
#pragma unroll
        for (int rr = 0; rr < 4; rr++) {
            Rs[w][q * 4 + rr][l16] = acc0[rr];
            Rs[w][q * 4 + rr][16 + l16] = acc1[rr];
        }
        __syncthreads();

        // ---- reduce 4 waves + tanh + coherent store of a col pair
        {
            float sA = Rs[0][em][en] + Rs[1][em][en] + Rs[2][em][en] + Rs[3][em][en];
            float sB = Rs[0][em][en + 1] + Rs[1][em][en + 1] + Rs[2][em][en + 1] + Rs[3][em][en + 1];
            ushort_t* dst = xall + (size_t)r * BH + (size_t)(b0 + em) * H_ + n0 + en;
            if (LAYER == 0) {
                unsigned xv = __hip_atomic_load((const unsigned*)dst,
                                                __ATOMIC_RELAXED, __HIP_MEMORY_SCOPE_SYSTEM);
                sA += bf2f((ushort_t)(xv & 0xffff));
                sB += bf2f((ushort_t)(xv >> 16));
            }
            sA += bv0;
            sB += bv1;
            unsigned pk = (unsigned)f2bf(tanhf(sA)) | ((unsigned)f2bf(tanhf(sB)) << 16);
            __hip_atomic_store((unsigned*)dst, pk, __ATOMIC_RELAXED, __HIP_MEMORY_SCOPE_SYSTEM);
        }

        // ---- group barrier on the recurrence (32 blocks per batch group)
        if (r < 511) {
            __syncthreads();  // vmcnt(0) drain: h stores LLC-visible before signal
            if (tid == 0) {
                __hip_atomic_fetch_add(cnt, 1, __ATOMIC_RELAXED, __HIP_MEMORY_SCOPE_SYSTEM);
                const int target = 32 * (r + 1);
                while (__hip_atomic_load(cnt, __ATOMIC_RELAXED, __HIP_MEMORY_SCOPE_SYSTEM) < target)
                    __builtin_amdgcn_s_sleep(1);
            }
            __syncthreads();
        }
    }
}

// ---------------------------------------------------------------- launch ----
extern "C" void kernel_launch(void* const* d_in, const int* in_sizes, int n_in,
                              void* d_out, int out_size, void* d_ws, size_t ws_size,
                              hipStream_t stream) {
    (void)in_sizes; (void)n_in; (void)out_size; (void)ws_size;
    const float* emb   = (const float*)d_in[0];
    const float* h0    = (const float*)d_in[1];
    const float* W_ih0 = (const float*)d_in[2];
    const float* b_ih0 = (const float*)d_in[3];
    const float* W_ih1 = (const float*)d_in[4];
    const float* b_ih1 = (const float*)d_in[5];
    const float* W_hh0 = (const float*)d_in[6];
    const float* b_hh0 = (const float*)d_in[7];
    const float* W_hh1 = (const float*)d_in[8];
    const float* b_hh1 = (const float*)d_in[9];
    const float* W_out = (const float*)d_in[10];
    const float* b_out = (const float*)d_in[11];
    float* out = (float*)d_out;

    char* ws = (char*)d_ws;
    int*      bar   = (int*)ws;                      // group counters (1024 ints)
    ushort_t* hinit = (ushort_t*)(ws + 4096);        // 2*B*H bf16
    ushort_t* xp    = (ushort_t*)(ws + 4096 + 2 * BH * 2);  // (T,B,H) bf16: x0 -> h0
    ushort_t* xq    = xp + (size_t)T_ * BH;                 // (T,B,H) bf16: h1

    prep_kernel<<<512, 256, 0, stream>>>(h0, hinit, bar);

    // xp = emb . W_ih0^T + b_ih0   (stored (T,B,H))
    gemm_bt<0><<<dim3(H_ / 128, (B_ * T_) / 128), 256, 0, stream>>>(
        emb, W_ih0, b_ih0, xp, H_, E_);

    // layer 0: xp := h0_all (in place)
    rnn_pass<0><<<128, 256, 0, stream>>>(xp, (const ushort_t*)nullptr, hinit,
                                         W_hh0, W_hh0, b_hh0, b_hh0, bar);

    // layer 1: xq := h1_all, x-term = h0_all . W_ih1^T computed in-kernel
    rnn_pass<1><<<128, 256, 0, stream>>>(xq, xp, hinit + BH,
                                         W_ih1, W_hh1, b_ih1, b_hh1, bar);

    // out = h1_all . W_out^T + b_out   ((B,T,O) fp32)
    gemm_bt<2><<<dim3(O_ / 128, (B_ * T_) / 128), 256, 0, stream>>>(
        xq, W_out, b_out, out, O_, H_);
}

// Round 6
// 2704.012 us; speedup vs baseline: 19.8300x; 1.1537x over previous
//
#include <hip/hip_runtime.h>
#include <cmath>

#define B_ 64
#define T_ 512
#define E_ 512
#define H_ 1024
#define O_ 512
#define BH (B_ * H_)
#define HSTRIDE 1160  // LDS row stride (elems)

typedef unsigned short ushort_t;
typedef __bf16 bf16x8 __attribute__((ext_vector_type(8)));
typedef float f32x4 __attribute__((ext_vector_type(4)));

__device__ __forceinline__ ushort_t f2bf(float f) {
    union { float f; unsigned int u; } x; x.f = f;
    unsigned int r = x.u + 0x7fffu + ((x.u >> 16) & 1u);
    return (ushort_t)(r >> 16);
}
__device__ __forceinline__ float bf2f(ushort_t u) {
    union { unsigned int u; float f; } x; x.u = ((unsigned int)u) << 16;
    return x.f;
}
__device__ __forceinline__ uint4 pack8bf(float4 v0, float4 v1) {
    uint4 pk;
    pk.x = (unsigned)f2bf(v0.x) | ((unsigned)f2bf(v0.y) << 16);
    pk.y = (unsigned)f2bf(v0.z) | ((unsigned)f2bf(v0.w) << 16);
    pk.z = (unsigned)f2bf(v1.x) | ((unsigned)f2bf(v1.y) << 16);
    pk.w = (unsigned)f2bf(v1.z) | ((unsigned)f2bf(v1.w) << 16);
    return pk;
}
__device__ __forceinline__ bf16x8 pack8(const float* src) {
    float4 v0 = *(const float4*)src;
    float4 v1 = *(const float4*)(src + 4);
    union { uint4 u; bf16x8 b; } c;
    c.u = pack8bf(v0, v1);
    return c.b;
}

// ---------------------------------------------------------------- prep ------
__global__ void prep_kernel(const float* __restrict__ h0, ushort_t* __restrict__ hinit,
                            int* __restrict__ bar) {
    int i = blockIdx.x * blockDim.x + threadIdx.x;
    if (i < 8192) bar[i] = 0;   // flag arrays: 2 layers x 4 groups x 32 flags x 32-int stride
    if (i < 2 * BH) hinit[i] = f2bf(h0[i]);
}

// ------------------------------------------------ big GEMM: C = A*W^T + b ---
// MODE 0: A fp32 (emb, (B,T,E), row r=t*64+b -> emb row (b,t)), out bf16 direct rows
// MODE 2: A bf16 direct rows, out fp32 remapped row r=t*64+b -> out row (b,t)
template <int MODE>
__launch_bounds__(256)
__global__ void gemm_bt(const void* __restrict__ Ap, const float* __restrict__ Wp,
                        const float* __restrict__ bias, void* __restrict__ outp,
                        int N, int K) {
    __shared__ __align__(16) ushort_t As[128 * 72];
    __shared__ __align__(16) ushort_t Bs[128 * 72];
    const int tid = threadIdx.x;
    const int lane = tid & 63;
    const int w = tid >> 6;
    const int wm = (w >> 1) * 64;
    const int wn = (w & 1) * 64;
    const int q = lane >> 4;
    const int l16 = lane & 15;
    const int m0 = blockIdx.y * 128;
    const int n0 = blockIdx.x * 128;

    const float*    Af = (const float*)Ap;
    const ushort_t* Ab = (const ushort_t*)Ap;

    f32x4 zero = {0.f, 0.f, 0.f, 0.f};
    f32x4 acc[4][4];
#pragma unroll
    for (int i = 0; i < 4; i++)
#pragma unroll
        for (int j = 0; j < 4; j++) acc[i][j] = zero;

    for (int k0 = 0; k0 < K; k0 += 64) {
#pragma unroll
        for (int it = 0; it < 4; it++) {
            int task = tid + it * 256;
            int row = task >> 3, seg = task & 7;
            if (MODE == 0) {
                int Ra = m0 + row;
                const float* src = Af + (size_t)((Ra & 63) * T_ + (Ra >> 6)) * K + k0 + seg * 8;
                float4 v0 = *(const float4*)src;
                float4 v1 = *(const float4*)(src + 4);
                *(uint4*)&As[row * 72 + seg * 8] = pack8bf(v0, v1);
            } else {
                const ushort_t* src = Ab + (size_t)(m0 + row) * K + k0 + seg * 8;
                *(uint4*)&As[row * 72 + seg * 8] = *(const uint4*)src;
            }
            const float* wsrc = Wp + (size_t)(n0 + row) * K + k0 + seg * 8;
            float4 w0 = *(const float4*)wsrc;
            float4 w1 = *(const float4*)(wsrc + 4);
            *(uint4*)&Bs[row * 72 + seg * 8] = pack8bf(w0, w1);
        }
        __syncthreads();
#pragma unroll
        for (int ks = 0; ks < 64; ks += 32) {
            bf16x8 af[4], bfr[4];
#pragma unroll
            for (int i = 0; i < 4; i++)
                af[i] = *(const bf16x8*)&As[(wm + i * 16 + l16) * 72 + ks + q * 8];
#pragma unroll
            for (int j = 0; j < 4; j++)
                bfr[j] = *(const bf16x8*)&Bs[(wn + j * 16 + l16) * 72 + ks + q * 8];
#pragma unroll
            for (int i = 0; i < 4; i++)
#pragma unroll
                for (int j = 0; j < 4; j++)
                    acc[i][j] = __builtin_amdgcn_mfma_f32_16x16x32_bf16(af[i], bfr[j], acc[i][j], 0, 0, 0);
        }
        __syncthreads();
    }

#pragma unroll
    for (int j = 0; j < 4; j++) {
        int C = n0 + wn + j * 16 + l16;
        float bv = bias[C];
#pragma unroll
        for (int i = 0; i < 4; i++) {
#pragma unroll
            for (int r = 0; r < 4; r++) {
                int R = m0 + wm + i * 16 + q * 4 + r;
                float v = acc[i][j][r] + bv;
                if (MODE == 2) {
                    ((float*)outp)[(size_t)((R & 63) * T_ + (R >> 6)) * N + C] = v;
                } else {
                    ((ushort_t*)outp)[(size_t)R * N + C] = f2bf(v);
                }
            }
        }
    }
}

// -------------------------- single-layer persistent recurrence (no skew) ----
// 128 blocks x 256 threads. Block (gb, cb): batch rows [16gb,+16), cols [32cb,+32).
// Barrier: per-block FLAG array (128B-strided words, zero write contention).
// Block cb signals flags[cb*32] = r+1; every wave polls all 32 flags with one
// vector load (lane i -> flags[(i&31)*32]) + __ballot. Flags are monotonic ->
// waves exit independently, no post-poll __syncthreads needed.
template <int LAYER>
__launch_bounds__(256, 1)
__global__ void rnn_pass(ushort_t* __restrict__ xall,
                         const ushort_t* __restrict__ xsrc,
                         const ushort_t* __restrict__ hin,
                         const float* __restrict__ Wa, const float* __restrict__ Wb,
                         const float* __restrict__ ba, const float* __restrict__ bb,
                         int* __restrict__ bar) {
    __shared__ __align__(16) ushort_t Hs0[16 * HSTRIDE];  // x-source rows (LAYER 1)
    __shared__ __align__(16) ushort_t Hs1[16 * HSTRIDE];  // recurrent-state rows
    __shared__ float Rs[4][16][33];

    const int tid = threadIdx.x;
    const int lane = tid & 63;
    const int w = tid >> 6;
    const int q = lane >> 4;
    const int l16 = lane & 15;
    const int gb = blockIdx.x >> 5;       // 4 batch groups x 32 col blocks
    const int cb = blockIdx.x & 31;
    const int b0 = gb * 16;
    const int n0 = cb * 32;
    int* flags = bar + (LAYER * 4 + gb) * 1024;   // 32 flags, 32-int (128B) stride
    int* pollp = flags + ((lane & 31) << 5);
    int* myflag = flags + (cb << 5);

    // ---- register B-fragments (loop-invariant weights)
    bf16x8 wA[16], wB[16];
#pragma unroll
    for (int g = 0; g < 2; g++)
#pragma unroll
        for (int kk = 0; kk < 8; kk++) {
            size_t off = (size_t)(n0 + g * 16 + l16) * H_ + w * 256 + kk * 32 + q * 8;
            wA[g * 8 + kk] = pack8(Wa + off);
            if (LAYER == 1) wB[g * 8 + kk] = pack8(Wb + off);
        }

    const int em = tid >> 4;
    const int en = (tid & 15) * 2;
    float bv0 = ba[n0 + en], bv1 = ba[n0 + en + 1];
    if (LAYER == 1) { bv0 += bb[n0 + en]; bv1 += bb[n0 + en + 1]; }

    const int rbase2 = (tid >> 7) * 2;  // 0 or 2
    const int seg = tid & 127;

    for (int r = 0; r < 512; r++) {
        uint4 d0, d1, d2, d3, d4, d5, d6, d7;
        if (LAYER == 1) {
            // ---- issue xsrc loads BEFORE the poll (barrier-independent,
            //      fully materialized by the previous dispatch; plain cached)
            const ushort_t* a0 = xsrc + (size_t)r * BH + (size_t)(b0 + rbase2) * H_ + seg * 8;
            const ushort_t* a1 = a0 + 4 * H_;
            const ushort_t* a2 = a0 + 8 * H_;
            const ushort_t* a3 = a0 + 12 * H_;
            asm volatile(
                "global_load_dwordx4 %0, %8, off\n\t"
                "global_load_dwordx4 %1, %8, off offset:2048\n\t"
                "global_load_dwordx4 %2, %9, off\n\t"
                "global_load_dwordx4 %3, %9, off offset:2048\n\t"
                "global_load_dwordx4 %4, %10, off\n\t"
                "global_load_dwordx4 %5, %10, off offset:2048\n\t"
                "global_load_dwordx4 %6, %11, off\n\t"
                "global_load_dwordx4 %7, %11, off offset:2048"
                : "=&v"(d0), "=&v"(d1), "=&v"(d2), "=&v"(d3),
                  "=&v"(d4), "=&v"(d5), "=&v"(d6), "=&v"(d7)
                : "v"(a0), "v"(a1), "v"(a2), "v"(a3)
                : "memory");
        }

        // ---- flag-array barrier wait: all 32 producer flags >= r
        if (r > 0) {
            while (true) {
                int v = __hip_atomic_load(pollp, __ATOMIC_RELAXED, __HIP_MEMORY_SCOPE_SYSTEM);
                if (__ballot(v >= r) == ~0ull) break;
            }
        }

        // ---- stage recurrent-state rows (LLC-coherent) [+ x word for LAYER 0]
        const ushort_t* s1 = (r == 0) ? hin : (xall + (size_t)(r - 1) * BH);
        const ushort_t* c0 = s1 + (size_t)(b0 + rbase2) * H_ + seg * 8;
        const ushort_t* c1 = c0 + 4 * H_;
        const ushort_t* c2 = c0 + 8 * H_;
        const ushort_t* c3 = c0 + 12 * H_;
        unsigned xw = 0;
        uint4 e0, e1, e2, e3, e4, e5, e6, e7;
        if (LAYER == 0) {
            const ushort_t* xaddr = xall + (size_t)r * BH + (size_t)(b0 + em) * H_ + n0 + en;
            asm volatile(
                "global_load_dwordx4 %0, %9, off sc0 sc1\n\t"
                "global_load_dwordx4 %1, %9, off offset:2048 sc0 sc1\n\t"
                "global_load_dwordx4 %2, %10, off sc0 sc1\n\t"
                "global_load_dwordx4 %3, %10, off offset:2048 sc0 sc1\n\t"
                "global_load_dwordx4 %4, %11, off sc0 sc1\n\t"
                "global_load_dwordx4 %5, %11, off offset:2048 sc0 sc1\n\t"
                "global_load_dwordx4 %6, %12, off sc0 sc1\n\t"
                "global_load_dwordx4 %7, %12, off offset:2048 sc0 sc1\n\t"
                "global_load_dword %8, %13, off sc0 sc1\n\t"
                "s_waitcnt vmcnt(0)"
                : "=&v"(e0), "=&v"(e1), "=&v"(e2), "=&v"(e3),
                  "=&v"(e4), "=&v"(e5), "=&v"(e6), "=&v"(e7), "=&v"(xw)
                : "v"(c0), "v"(c1), "v"(c2), "v"(c3), "v"(xaddr)
                : "memory");
        } else {
            asm volatile(
                "global_load_dwordx4 %0, %8, off sc0 sc1\n\t"
                "global_load_dwordx4 %1, %8, off offset:2048 sc0 sc1\n\t"
                "global_load_dwordx4 %2, %9, off sc0 sc1\n\t"
                "global_load_dwordx4 %3, %9, off offset:2048 sc0 sc1\n\t"
                "global_load_dwordx4 %4, %10, off sc0 sc1\n\t"
                "global_load_dwordx4 %5, %10, off offset:2048 sc0 sc1\n\t"
                "global_load_dwordx4 %6, %11, off sc0 sc1\n\t"
                "global_load_dwordx4 %7, %11, off offset:2048 sc0 sc1\n\t"
                "s_waitcnt vmcnt(0)"
                : "=&v"(e0), "=&v"(e1), "=&v"(e2), "=&v"(e3),
                  "=&v"(e4), "=&v"(e5), "=&v"(e6), "=&v"(e7)
                : "v"(c0), "v"(c1), "v"(c2), "v"(c3)
                : "memory");
            // xsrc tile -> Hs0 (d's valid: vmcnt(0) above drained them too)
            *(uint4*)&Hs0[(rbase2 + 0) * HSTRIDE + seg * 8] = d0;
            *(uint4*)&Hs0[(rbase2 + 1) * HSTRIDE + seg * 8] = d1;
            *(uint4*)&Hs0[(rbase2 + 4) * HSTRIDE + seg * 8] = d2;
            *(uint4*)&Hs0[(rbase2 + 5) * HSTRIDE + seg * 8] = d3;
            *(uint4*)&Hs0[(rbase2 + 8) * HSTRIDE + seg * 8] = d4;
            *(uint4*)&Hs0[(rbase2 + 9) * HSTRIDE + seg * 8] = d5;
            *(uint4*)&Hs0[(rbase2 + 12) * HSTRIDE + seg * 8] = d6;
            *(uint4*)&Hs0[(rbase2 + 13) * HSTRIDE + seg * 8] = d7;
        }
        *(uint4*)&Hs1[(rbase2 + 0) * HSTRIDE + seg * 8] = e0;
        *(uint4*)&Hs1[(rbase2 + 1) * HSTRIDE + seg * 8] = e1;
        *(uint4*)&Hs1[(rbase2 + 4) * HSTRIDE + seg * 8] = e2;
        *(uint4*)&Hs1[(rbase2 + 5) * HSTRIDE + seg * 8] = e3;
        *(uint4*)&Hs1[(rbase2 + 8) * HSTRIDE + seg * 8] = e4;
        *(uint4*)&Hs1[(rbase2 + 9) * HSTRIDE + seg * 8] = e5;
        *(uint4*)&Hs1[(rbase2 + 12) * HSTRIDE + seg * 8] = e6;
        *(uint4*)&Hs1[(rbase2 + 13) * HSTRIDE + seg * 8] = e7;
        __syncthreads();

        // ---- MFMA: wave w covers K slice [256w,+256), both 16-col groups
        f32x4 acc0 = {0.f, 0.f, 0.f, 0.f};
        f32x4 acc1 = {0.f, 0.f, 0.f, 0.f};
        const int kb = w * 256;
        if (LAYER == 1) {
#pragma unroll
            for (int kk = 0; kk < 8; kk++) {
                bf16x8 a = *(const bf16x8*)&Hs0[l16 * HSTRIDE + kb + kk * 32 + q * 8];
                acc0 = __builtin_amdgcn_mfma_f32_16x16x32_bf16(a, wA[kk], acc0, 0, 0, 0);
                acc1 = __builtin_amdgcn_mfma_f32_16x16x32_bf16(a, wA[8 + kk], acc1, 0, 0, 0);
            }
#pragma unroll
            for (int kk = 0; kk < 8; kk++) {
                bf16x8 a = *(const bf16x8*)&Hs1[l16 * HSTRIDE + kb + kk * 32 + q * 8];
                acc0 = __builtin_amdgcn_mfma_f32_16x16x32_bf16(a, wB[kk], acc0, 0, 0, 0);
                acc1 = __builtin_amdgcn_mfma_f32_16x16x32_bf16(a, wB[8 + kk], acc1, 0, 0, 0);
            }
        } else {
#pragma unroll
            for (int kk = 0; kk < 8; kk++) {
                bf16x8 a = *(const bf16x8*)&Hs1[l16 * HSTRIDE + kb + kk * 32 + q * 8];
                acc0 = __builtin_amdgcn_mfma_f32_16x16x32_bf16(a, wA[kk], acc0, 0, 0, 0);
                acc1 = __builtin_amdgcn_mfma_f32_16x16x32_bf16(a, wA[8 + kk], acc1, 0, 0, 0);
            }
        }
#pragma unroll
        for (int rr = 0; rr < 4; rr++) {
            Rs[w][q * 4 + rr][l16] = acc0[rr];
            Rs[w][q * 4 + rr][16 + l16] = acc1[rr];
        }
        __syncthreads();

        // ---- reduce 4 waves + tanh + coherent store of a col pair
        {
            float sA = Rs[0][em][en] + Rs[1][em][en] + Rs[2][em][en] + Rs[3][em][en];
            float sB = Rs[0][em][en + 1] + Rs[1][em][en + 1] + Rs[2][em][en + 1] + Rs[3][em][en + 1];
            ushort_t* dst = xall + (size_t)r * BH + (size_t)(b0 + em) * H_ + n0 + en;
            if (LAYER == 0) {
                sA += bf2f((ushort_t)(xw & 0xffff));
                sB += bf2f((ushort_t)(xw >> 16));
            }
            sA += bv0;
            sB += bv1;
            unsigned pk = (unsigned)f2bf(tanhf(sA)) | ((unsigned)f2bf(tanhf(sB)) << 16);
            __hip_atomic_store((unsigned*)dst, pk, __ATOMIC_RELAXED, __HIP_MEMORY_SCOPE_SYSTEM);
        }

        // ---- signal: drain stores, then publish this block's flag
        if (r < 511) {
            __syncthreads();  // vmcnt(0) drain: h stores LLC-visible before flag
            if (tid == 0)
                __hip_atomic_store(myflag, r + 1, __ATOMIC_RELAXED, __HIP_MEMORY_SCOPE_SYSTEM);
        }
    }
}

// ---------------------------------------------------------------- launch ----
extern "C" void kernel_launch(void* const* d_in, const int* in_sizes, int n_in,
                              void* d_out, int out_size, void* d_ws, size_t ws_size,
                              hipStream_t stream) {
    (void)in_sizes; (void)n_in; (void)out_size; (void)ws_size;
    const float* emb   = (const float*)d_in[0];
    const float* h0    = (const float*)d_in[1];
    const float* W_ih0 = (const float*)d_in[2];
    const float* b_ih0 = (const float*)d_in[3];
    const float* W_ih1 = (const float*)d_in[4];
    const float* b_ih1 = (const float*)d_in[5];
    const float* W_hh0 = (const float*)d_in[6];
    const float* b_hh0 = (const float*)d_in[7];
    const float* W_hh1 = (const float*)d_in[8];
    const float* b_hh1 = (const float*)d_in[9];
    const float* W_out = (const float*)d_in[10];
    const float* b_out = (const float*)d_in[11];
    float* out = (float*)d_out;

    char* ws = (char*)d_ws;
    int*      bar   = (int*)ws;                      // flag arrays (8192 ints)
    ushort_t* hinit = (ushort_t*)(ws + 65536);       // 2*B*H bf16
    ushort_t* xp    = (ushort_t*)(ws + 65536 + 2 * BH * 2);  // (T,B,H) bf16: x0 -> h0
    ushort_t* xq    = xp + (size_t)T_ * BH;                  // (T,B,H) bf16: h1

    prep_kernel<<<512, 256, 0, stream>>>(h0, hinit, bar);

    // xp = emb . W_ih0^T + b_ih0   (stored (T,B,H))
    gemm_bt<0><<<dim3(H_ / 128, (B_ * T_) / 128), 256, 0, stream>>>(
        emb, W_ih0, b_ih0, xp, H_, E_);

    // layer 0: xp := h0_all (in place)
    rnn_pass<0><<<128, 256, 0, stream>>>(xp, (const ushort_t*)nullptr, hinit,
                                         W_hh0, W_hh0, b_hh0, b_hh0, bar);

    // layer 1: xq := h1_all, x-term = h0_all . W_ih1^T computed in-kernel
    rnn_pass<1><<<128, 256, 0, stream>>>(xq, xp, hinit + BH,
                                         W_ih1, W_hh1, b_ih1, b_hh1, bar);

    // out = h1_all . W_out^T + b_out   ((B,T,O) fp32)
    gemm_bt<2><<<dim3(O_ / 128, (B_ * T_) / 128), 256, 0, stream>>>(
        xq, W_out, b_out, out, O_, H_);
}